// Round 6
// baseline (401.681 us; speedup 1.0000x reference)
//
#include <hip/hip_runtime.h>
#include <hip/hip_bf16.h>
#include <cstdint>

#define N_NODES 100000
#define HID 128
#define NBINS 391            // ceil(100000/256)
#define CHUNK 4096

typedef __attribute__((ext_vector_type(8))) short short8v;
typedef __attribute__((ext_vector_type(4))) float floatx4;

__device__ __forceinline__ float bflo(unsigned v) { return __uint_as_float(v << 16); }
__device__ __forceinline__ float bfhi(unsigned v) { return __uint_as_float(v & 0xffff0000u); }
__device__ __forceinline__ unsigned short f2bf(float f) {
    unsigned u = __float_as_uint(f);
    unsigned r = (u + 0x7fffu + ((u >> 16) & 1u)) >> 16;
    return (unsigned short)r;
}

// ---------------- prep: fp32->bf16 convert (x) + weight pack, one launch ----------------
__global__ __launch_bounds__(256) void prep_kernel(const float* __restrict__ x,
                                                   unsigned short* __restrict__ xb, int total8,
                                                   const float* __restrict__ Wl0, const float* __restrict__ Wr0,
                                                   const float* __restrict__ Wl1, const float* __restrict__ Wr1,
                                                   const float* __restrict__ Wl2, const float* __restrict__ Wr2,
                                                   unsigned short* __restrict__ Bp) {
    if ((int)blockIdx.x < total8 / 256) {
        int i = blockIdx.x * 256 + threadIdx.x;
        const float4* p = (const float4*)x + (size_t)i * 2;
        float4 a = p[0], b = p[1];
        uint4 o;
        o.x = f2bf(a.x) | ((unsigned)f2bf(a.y) << 16);
        o.y = f2bf(a.z) | ((unsigned)f2bf(a.w) << 16);
        o.z = f2bf(b.x) | ((unsigned)f2bf(b.y) << 16);
        o.w = f2bf(b.z) | ((unsigned)f2bf(b.w) << 16);
        *(uint4*)(xb + (size_t)i * 8) = o;
    } else {
        int idx = ((int)blockIdx.x - total8 / 256) * 256 + threadIdx.x;
        if (idx >= 12288) return;
        int g = idx & 3, c = (idx >> 2) & 127, s = (idx >> 9) & 3, t = (idx >> 11) & 1, L = idx >> 12;
        const float* W = (t == 0) ? (L == 0 ? Wl0 : (L == 1 ? Wl1 : Wl2))
                                  : (L == 0 ? Wr0 : (L == 1 ? Wr1 : Wr2));
        int k0 = s * 32 + g * 8;
        uint4 o;
        o.x = f2bf(W[(k0 + 0) * 128 + c]) | ((unsigned)f2bf(W[(k0 + 1) * 128 + c]) << 16);
        o.y = f2bf(W[(k0 + 2) * 128 + c]) | ((unsigned)f2bf(W[(k0 + 3) * 128 + c]) << 16);
        o.z = f2bf(W[(k0 + 4) * 128 + c]) | ((unsigned)f2bf(W[(k0 + 5) * 128 + c]) << 16);
        o.w = f2bf(W[(k0 + 6) * 128 + c]) | ((unsigned)f2bf(W[(k0 + 7) * 128 + c]) << 16);
        size_t chunk = (((size_t)(L * 2 + t) * 4 + s) * 128 + c) * 4 + g;
        *(uint4*)(Bp + chunk * 8) = o;
    }
}

// ---------------- CSR build: atomic-free bucket sort ----------------

__global__ __launch_bounds__(256) void binhist_kernel(const int* __restrict__ dst,
                                                      int* __restrict__ cntMat, int E) {
    __shared__ int lcnt[512];
    const int tid = threadIdx.x;
    lcnt[tid] = 0; lcnt[tid + 256] = 0;
    __syncthreads();
    int base = blockIdx.x * CHUNK;
    int end = base + CHUNK; if (end > E) end = E;
    for (int i = base + tid; i < end; i += 256) atomicAdd(&lcnt[dst[i] >> 8], 1);
    __syncthreads();
    for (int j = tid; j < NBINS; j += 256) cntMat[(size_t)blockIdx.x * NBINS + j] = lcnt[j];
}

__global__ __launch_bounds__(512) void colscan_kernel(int* __restrict__ cntMat,
                                                      int* __restrict__ binCnt, int nch) {
    __shared__ int wsum[8];
    const int j = blockIdx.x;
    const int tid = threadIdx.x;
    const int lane = tid & 63, w = tid >> 6;
    int v = (tid < nch) ? cntMat[(size_t)tid * NBINS + j] : 0;
    int s = v;
    #pragma unroll
    for (int o = 1; o < 64; o <<= 1) {
        int t = __shfl_up(s, o, 64);
        if (lane >= o) s += t;
    }
    if (lane == 63) wsum[w] = s;
    __syncthreads();
    if (w == 0 && lane < 8) {
        int t = wsum[lane];
        int ss = t;
        #pragma unroll
        for (int o = 1; o < 8; o <<= 1) {
            int u = __shfl_up(ss, o, 64);
            if (lane >= o) ss += u;
        }
        wsum[lane] = ss - t;
    }
    __syncthreads();
    int excl = (s - v) + wsum[w];
    if (tid < nch) cntMat[(size_t)tid * NBINS + j] = excl;
    if (tid == 511) binCnt[j] = excl + v;
}

__global__ __launch_bounds__(512) void binbase_kernel(const int* __restrict__ binCnt,
                                                      int* __restrict__ binBase,
                                                      int* __restrict__ offs, int E) {
    __shared__ int wsum[8];
    const int tid = threadIdx.x;
    const int lane = tid & 63, w = tid >> 6;
    int v = (tid < NBINS) ? binCnt[tid] : 0;
    int s = v;
    #pragma unroll
    for (int o = 1; o < 64; o <<= 1) {
        int t = __shfl_up(s, o, 64);
        if (lane >= o) s += t;
    }
    if (lane == 63) wsum[w] = s;
    __syncthreads();
    if (w == 0 && lane < 8) {
        int t = wsum[lane];
        int ss = t;
        #pragma unroll
        for (int o = 1; o < 8; o <<= 1) {
            int u = __shfl_up(ss, o, 64);
            if (lane >= o) ss += u;
        }
        wsum[lane] = ss - t;
    }
    __syncthreads();
    if (tid < NBINS) binBase[tid] = (s - v) + wsum[w];
    if (tid == 0) offs[N_NODES] = E;
}

__global__ __launch_bounds__(256) void binscat_kernel(const int* __restrict__ src, const int* __restrict__ dst,
                                                      const int* __restrict__ cntMat,
                                                      const int* __restrict__ binBase,
                                                      unsigned* __restrict__ binned, int E) {
    __shared__ int cur[512];
    const int tid = threadIdx.x;
    const int row = blockIdx.x;
    for (int j = tid; j < NBINS; j += 256) cur[j] = cntMat[(size_t)row * NBINS + j] + binBase[j];
    __syncthreads();
    int base = row * CHUNK;
    int end = base + CHUNK; if (end > E) end = E;
    for (int i = base + tid; i < end; i += 256) {
        int d = dst[i];
        int s = src[i];
        int bin = d >> 8;
        int pos = atomicAdd(&cur[bin], 1);
        binned[pos] = (unsigned)s | ((unsigned)(d & 255) << 20);
    }
}

__global__ __launch_bounds__(256) void bincsr_kernel(const unsigned* __restrict__ binned,
                                                     const int* __restrict__ binBase, const int* __restrict__ binCnt,
                                                     int* __restrict__ esrc, int* __restrict__ offs) {
    __shared__ int h[256];
    __shared__ int cur[256];
    __shared__ int ssrc[8192];
    const int tid = threadIdx.x;
    const int bin = blockIdx.x;
    const int base = binBase[bin];
    const int cnt = binCnt[bin];
    h[tid] = 0;
    __syncthreads();
    for (int i = tid; i < cnt; i += 256) atomicAdd(&h[binned[base + i] >> 20], 1);
    __syncthreads();
    int v = h[tid];
    for (int o = 1; o < 256; o <<= 1) {
        int t = (tid >= o) ? h[tid - o] : 0;
        __syncthreads();
        h[tid] += t;
        __syncthreads();
    }
    int excl = h[tid] - v;
    cur[tid] = excl;
    int node = (bin << 8) + tid;
    if (node < N_NODES) offs[node] = base + excl;
    __syncthreads();
    for (int i = tid; i < cnt; i += 256) {
        unsigned p = binned[base + i];
        int pos = atomicAdd(&cur[p >> 20], 1);
        int s = (int)(p & 0xFFFFFu);
        if (pos < 8192) ssrc[pos] = s;
        else esrc[base + pos] = s;
    }
    __syncthreads();
    int lim = cnt < 8192 ? cnt : 8192;
    for (int i = tid; i < lim; i += 256) esrc[base + i] = ssrc[i];
}

// ---------------- fused layer: gather-mean (to LDS) + MFMA GEMM + epilogue ----------------
// block = 64 nodes, 256 threads / 4 waves.
// At[0..8191]   : mean tile (bf16, swizzled slot^ (row&15)) -- written by gather phase
// At[8192..]    : h tile, staged via global_load_lds (pre-swizzled global source)
__global__ __launch_bounds__(256) void fused_kernel(const unsigned short* __restrict__ hin,
                                                    const int* __restrict__ offs,
                                                    const int* __restrict__ esrc,
                                                    const unsigned short* __restrict__ Bp,
                                                    const float* __restrict__ bias,
                                                    const float* __restrict__ Wsl,
                                                    unsigned short* __restrict__ hout,
                                                    float* __restrict__ score,
                                                    const float* __restrict__ rrs,
                                                    const float* __restrict__ bsp,
                                                    const float* __restrict__ alphap,
                                                    float* __restrict__ outF,
                                                    const int accum, const int writeH, const int doFinal) {
    __shared__ unsigned short At[2 * 64 * 128];
    __shared__ float sred[2][64];
    const int tid = threadIdx.x;
    const int lane = tid & 63;
    const int w = tid >> 6;
    const int rowBase = blockIdx.x * 64;

    // (a) issue h-tile staging first; latency hides under the gather phase
    #pragma unroll
    for (int r = 0; r < 4; ++r) {
        int c = r * 256 + tid;
        int row = c >> 4, slot = c & 15;
        int gslot = slot ^ (row & 15);
        int grow = rowBase + row; if (grow >= N_NODES) grow = N_NODES - 1;
        const unsigned short* gp = hin + (size_t)grow * HID + gslot * 8;
        unsigned ldsOff = 16384u + (unsigned)(r * 4096 + w * 1024);
        __builtin_amdgcn_global_load_lds((const __attribute__((address_space(1))) void*)gp,
                                         (__attribute__((address_space(3))) void*)((char*)At + ldsOff),
                                         16, 0, 0);
    }

    // (b) gather-mean: each wave owns 16 nodes; uint2/lane, 2 rows per load pass
    const int half = lane >> 5;
    const int fl = lane & 31;
    for (int k = 0; k < 16; ++k) {
        const int nl = w * 16 + k;
        const int node = rowBase + nl;
        float a0 = 0.f, a1 = 0.f, a2 = 0.f, a3 = 0.f;
        int nb = 0;
        if (node < N_NODES) {
            const int beg = offs[node], end = offs[node + 1];
            nb = end - beg;
            for (int base = 0; base < nb; base += 64) {
                int m = nb - base; if (m > 64) m = 64;
                int sv = (lane < m) ? esrc[beg + base + lane] : 0;
                int j = 0;
                for (; j + 16 <= m; j += 16) {
                    uint2 v[8];
                    #pragma unroll
                    for (int p = 0; p < 8; ++p) {
                        int s = __shfl(sv, j + 2 * p + half, 64);
                        v[p] = *(const uint2*)(hin + (size_t)s * HID + fl * 4);
                    }
                    #pragma unroll
                    for (int p = 0; p < 8; ++p) {
                        a0 += bflo(v[p].x); a1 += bfhi(v[p].x);
                        a2 += bflo(v[p].y); a3 += bfhi(v[p].y);
                    }
                }
                for (; j + 2 <= m; j += 2) {
                    int s = __shfl(sv, j + half, 64);
                    uint2 vv = *(const uint2*)(hin + (size_t)s * HID + fl * 4);
                    a0 += bflo(vv.x); a1 += bfhi(vv.x);
                    a2 += bflo(vv.y); a3 += bfhi(vv.y);
                }
                if (j < m) {
                    int s = __shfl(sv, j, 64);
                    if (half == 0) {
                        uint2 vv = *(const uint2*)(hin + (size_t)s * HID + fl * 4);
                        a0 += bflo(vv.x); a1 += bfhi(vv.x);
                        a2 += bflo(vv.y); a3 += bfhi(vv.y);
                    }
                }
            }
        }
        a0 += __shfl_xor(a0, 32, 64);
        a1 += __shfl_xor(a1, 32, 64);
        a2 += __shfl_xor(a2, 32, 64);
        a3 += __shfl_xor(a3, 32, 64);
        if (half == 0) {
            float inv = 1.f / (float)(nb > 0 ? nb : 1);
            uint2 o;
            o.x = (unsigned)f2bf(a0 * inv) | ((unsigned)f2bf(a1 * inv) << 16);
            o.y = (unsigned)f2bf(a2 * inv) | ((unsigned)f2bf(a3 * inv) << 16);
            // swizzled mean-tile write: slot' = (fl>>1) ^ (nl&15), half-chunk (fl&1)
            int sw = (fl >> 1) ^ (nl & 15);
            *(uint2*)&At[nl * 128 + sw * 8 + (fl & 1) * 4] = o;
        }
    }
    __syncthreads();

    // (c) MFMA: 4 waves (wm = w&1 row-half, wn = w>>1 col-half)
    const int wm = w & 1, wn = w >> 1;
    const int halfRow = lane & 15;
    const int g = lane >> 4;

    floatx4 acc[2][4];
    #pragma unroll
    for (int m = 0; m < 2; m++)
        #pragma unroll
        for (int n = 0; n < 4; n++) acc[m][n] = (floatx4){0.f, 0.f, 0.f, 0.f};

    #pragma unroll
    for (int t = 0; t < 2; t++) {
        #pragma unroll
        for (int s = 0; s < 4; s++) {
            int slot = (s * 4 + g) ^ halfRow;
            int row0 = wm * 32 + halfRow;
            short8v a0 = *(const short8v*)&At[t * 8192 + row0 * 128 + slot * 8];
            short8v a1 = *(const short8v*)&At[t * 8192 + (row0 + 16) * 128 + slot * 8];
            #pragma unroll
            for (int n = 0; n < 4; n++) {
                int col = wn * 64 + n * 16 + halfRow;
                short8v b = *(const short8v*)&Bp[((((size_t)(t * 4 + s)) * 128 + col) * 4 + g) * 8];
                acc[0][n] = __builtin_amdgcn_mfma_f32_16x16x32_bf16(a0, b, acc[0][n], 0, 0, 0);
                acc[1][n] = __builtin_amdgcn_mfma_f32_16x16x32_bf16(a1, b, acc[1][n], 0, 0, 0);
            }
        }
    }

    // (d) epilogue: bias + ReLU + bf16 store + per-row score partial (+ optional final blend)
    #pragma unroll
    for (int m = 0; m < 2; m++) {
        #pragma unroll
        for (int i = 0; i < 4; i++) {
            int rloc = wm * 32 + m * 16 + g * 4 + i;
            int grow = rowBase + rloc;
            float ps = 0.f;
            #pragma unroll
            for (int n = 0; n < 4; n++) {
                int col = wn * 64 + n * 16 + halfRow;
                float v = acc[m][n][i] + bias[col];
                v = fmaxf(v, 0.f);
                if (writeH && grow < N_NODES) hout[(size_t)grow * HID + col] = f2bf(v);
                ps += v * Wsl[col];
            }
            ps += __shfl_xor(ps, 1, 64);
            ps += __shfl_xor(ps, 2, 64);
            ps += __shfl_xor(ps, 4, 64);
            ps += __shfl_xor(ps, 8, 64);
            if (halfRow == 0) sred[wn][rloc] = ps;
        }
    }
    __syncthreads();
    if (w == 0) {
        int grow = rowBase + lane;
        if (grow < N_NODES) {
            float tot = sred[0][lane] + sred[1][lane];
            if (doFinal) {
                float sc = score[grow] + tot;
                float a = 1.f / (1.f + __expf(-alphap[0]));
                outF[grow] = a * rrs[grow] + (1.f - a) * (sc + bsp[0]);
            } else {
                score[grow] = accum ? (score[grow] + tot) : tot;
            }
        }
    }
}

extern "C" void kernel_launch(void* const* d_in, const int* in_sizes, int n_in,
                              void* d_out, int out_size, void* d_ws, size_t ws_size,
                              hipStream_t stream) {
    const float* x     = (const float*)d_in[0];
    const int*   eidx  = (const int*)d_in[1];
    const float* rrs   = (const float*)d_in[2];
    const float* Wl0   = (const float*)d_in[3];
    const float* Wr0   = (const float*)d_in[4];
    const float* b0    = (const float*)d_in[5];
    const float* Wl1   = (const float*)d_in[6];
    const float* Wr1   = (const float*)d_in[7];
    const float* b1    = (const float*)d_in[8];
    const float* Wl2   = (const float*)d_in[9];
    const float* Wr2   = (const float*)d_in[10];
    const float* b2    = (const float*)d_in[11];
    const float* Ws    = (const float*)d_in[12];
    const float* bs    = (const float*)d_in[13];
    const float* alpha = (const float*)d_in[14];

    const int N = N_NODES;
    const int E = in_sizes[1] / 2;
    const int* src = eidx;
    const int* dst = eidx + E;

    uintptr_t p = (uintptr_t)d_ws;
    auto alloc = [&](size_t bytes) -> void* {
        p = (p + 255) & ~(uintptr_t)255;
        void* r = (void*)p;
        p += bytes;
        return r;
    };
    int*            offs    = (int*)alloc((size_t)(N + 1) * 4);
    int*            esrc    = (int*)alloc((size_t)E * 4);
    float*          score   = (float*)alloc((size_t)N * 4);
    int*            binBase = (int*)alloc(512 * 4);
    int*            binCnt  = (int*)alloc(512 * 4);
    unsigned short* xb      = (unsigned short*)alloc((size_t)N * HID * 2);
    unsigned short* bufA    = (unsigned short*)alloc((size_t)N * HID * 2);
    unsigned short* bufB    = (unsigned short*)alloc((size_t)N * HID * 2);
    unsigned short* Bp      = (unsigned short*)alloc((size_t)3 * 32768 * 2);

    int*      cntMat = (int*)bufA;
    unsigned* binned = (unsigned*)bufB;

    const int nch = (E + CHUNK - 1) / CHUNK;   // 391

    prep_kernel<<<N * HID / 8 / 256 + 48, 256, 0, stream>>>(x, xb, N * HID / 8,
                                                            Wl0, Wr0, Wl1, Wr1, Wl2, Wr2, Bp);

    binhist_kernel<<<nch, 256, 0, stream>>>(dst, cntMat, E);
    colscan_kernel<<<NBINS, 512, 0, stream>>>(cntMat, binCnt, nch);
    binbase_kernel<<<1, 512, 0, stream>>>(binCnt, binBase, offs, E);
    binscat_kernel<<<nch, 256, 0, stream>>>(src, dst, cntMat, binBase, binned, E);
    bincsr_kernel<<<NBINS, 256, 0, stream>>>(binned, binBase, binCnt, esrc, offs);

    const int gemmGrid = (N + 63) / 64;   // 1563
    float* outF = (float*)d_out;

    // layer 0: hin = xb, hout = bufA
    fused_kernel<<<gemmGrid, 256, 0, stream>>>(xb, offs, esrc, Bp + 0 * 32768, b0, Ws + 0 * HID,
                                               bufA, score, rrs, bs, alpha, outF, 0, 1, 0);
    // layer 1: hin = bufA, hout = bufB
    fused_kernel<<<gemmGrid, 256, 0, stream>>>(bufA, offs, esrc, Bp + 1 * 32768, b1, Ws + 1 * HID,
                                               bufB, score, rrs, bs, alpha, outF, 1, 1, 0);
    // layer 2: hin = bufB, final blend into d_out
    fused_kernel<<<gemmGrid, 256, 0, stream>>>(bufB, offs, esrc, Bp + 2 * 32768, b2, Ws + 2 * HID,
                                               bufB, score, rrs, bs, alpha, outF, 1, 0, 1);
}

// Round 7
// 398.941 us; speedup vs baseline: 1.0069x; 1.0069x over previous
//
#include <hip/hip_runtime.h>
#include <hip/hip_bf16.h>
#include <cstdint>

#define N_NODES 100000
#define HID 128
#define NBINS 391            // ceil(100000/256)
#define CHUNK 4096

typedef __attribute__((ext_vector_type(8))) short short8v;
typedef __attribute__((ext_vector_type(4))) float floatx4;

__device__ __forceinline__ float bflo(unsigned v) { return __uint_as_float(v << 16); }
__device__ __forceinline__ float bfhi(unsigned v) { return __uint_as_float(v & 0xffff0000u); }
__device__ __forceinline__ unsigned short f2bf(float f) {
    unsigned u = __float_as_uint(f);
    unsigned r = (u + 0x7fffu + ((u >> 16) & 1u)) >> 16;
    return (unsigned short)r;
}

// ---------------- prep: fp32->bf16 convert (x) + weight pack, one launch ----------------
__global__ __launch_bounds__(256) void prep_kernel(const float* __restrict__ x,
                                                   unsigned short* __restrict__ xb, int total8,
                                                   const float* __restrict__ Wl0, const float* __restrict__ Wr0,
                                                   const float* __restrict__ Wl1, const float* __restrict__ Wr1,
                                                   const float* __restrict__ Wl2, const float* __restrict__ Wr2,
                                                   unsigned short* __restrict__ Bp) {
    if ((int)blockIdx.x < total8 / 256) {
        int i = blockIdx.x * 256 + threadIdx.x;
        const float4* p = (const float4*)x + (size_t)i * 2;
        float4 a = p[0], b = p[1];
        uint4 o;
        o.x = f2bf(a.x) | ((unsigned)f2bf(a.y) << 16);
        o.y = f2bf(a.z) | ((unsigned)f2bf(a.w) << 16);
        o.z = f2bf(b.x) | ((unsigned)f2bf(b.y) << 16);
        o.w = f2bf(b.z) | ((unsigned)f2bf(b.w) << 16);
        *(uint4*)(xb + (size_t)i * 8) = o;
    } else {
        int idx = ((int)blockIdx.x - total8 / 256) * 256 + threadIdx.x;
        if (idx >= 12288) return;
        int g = idx & 3, c = (idx >> 2) & 127, s = (idx >> 9) & 3, t = (idx >> 11) & 1, L = idx >> 12;
        const float* W = (t == 0) ? (L == 0 ? Wl0 : (L == 1 ? Wl1 : Wl2))
                                  : (L == 0 ? Wr0 : (L == 1 ? Wr1 : Wr2));
        int k0 = s * 32 + g * 8;
        uint4 o;
        o.x = f2bf(W[(k0 + 0) * 128 + c]) | ((unsigned)f2bf(W[(k0 + 1) * 128 + c]) << 16);
        o.y = f2bf(W[(k0 + 2) * 128 + c]) | ((unsigned)f2bf(W[(k0 + 3) * 128 + c]) << 16);
        o.z = f2bf(W[(k0 + 4) * 128 + c]) | ((unsigned)f2bf(W[(k0 + 5) * 128 + c]) << 16);
        o.w = f2bf(W[(k0 + 6) * 128 + c]) | ((unsigned)f2bf(W[(k0 + 7) * 128 + c]) << 16);
        size_t chunk = (((size_t)(L * 2 + t) * 4 + s) * 128 + c) * 4 + g;
        *(uint4*)(Bp + chunk * 8) = o;
    }
}

// ---------------- CSR build: atomic-free bucket sort ----------------

__global__ __launch_bounds__(256) void binhist_kernel(const int* __restrict__ dst,
                                                      int* __restrict__ cntMat, int E) {
    __shared__ int lcnt[512];
    const int tid = threadIdx.x;
    lcnt[tid] = 0; lcnt[tid + 256] = 0;
    __syncthreads();
    int base = blockIdx.x * CHUNK;
    int end = base + CHUNK; if (end > E) end = E;
    for (int i = base + tid; i < end; i += 256) atomicAdd(&lcnt[dst[i] >> 8], 1);
    __syncthreads();
    for (int j = tid; j < NBINS; j += 256) cntMat[(size_t)blockIdx.x * NBINS + j] = lcnt[j];
}

__global__ __launch_bounds__(512) void colscan_kernel(int* __restrict__ cntMat,
                                                      int* __restrict__ binCnt, int nch) {
    __shared__ int wsum[8];
    const int j = blockIdx.x;
    const int tid = threadIdx.x;
    const int lane = tid & 63, w = tid >> 6;
    int v = (tid < nch) ? cntMat[(size_t)tid * NBINS + j] : 0;
    int s = v;
    #pragma unroll
    for (int o = 1; o < 64; o <<= 1) {
        int t = __shfl_up(s, o, 64);
        if (lane >= o) s += t;
    }
    if (lane == 63) wsum[w] = s;
    __syncthreads();
    if (w == 0 && lane < 8) {
        int t = wsum[lane];
        int ss = t;
        #pragma unroll
        for (int o = 1; o < 8; o <<= 1) {
            int u = __shfl_up(ss, o, 64);
            if (lane >= o) ss += u;
        }
        wsum[lane] = ss - t;
    }
    __syncthreads();
    int excl = (s - v) + wsum[w];
    if (tid < nch) cntMat[(size_t)tid * NBINS + j] = excl;
    if (tid == 511) binCnt[j] = excl + v;
}

__global__ __launch_bounds__(512) void binbase_kernel(const int* __restrict__ binCnt,
                                                      int* __restrict__ binBase,
                                                      int* __restrict__ offs, int E) {
    __shared__ int wsum[8];
    const int tid = threadIdx.x;
    const int lane = tid & 63, w = tid >> 6;
    int v = (tid < NBINS) ? binCnt[tid] : 0;
    int s = v;
    #pragma unroll
    for (int o = 1; o < 64; o <<= 1) {
        int t = __shfl_up(s, o, 64);
        if (lane >= o) s += t;
    }
    if (lane == 63) wsum[w] = s;
    __syncthreads();
    if (w == 0 && lane < 8) {
        int t = wsum[lane];
        int ss = t;
        #pragma unroll
        for (int o = 1; o < 8; o <<= 1) {
            int u = __shfl_up(ss, o, 64);
            if (lane >= o) ss += u;
        }
        wsum[lane] = ss - t;
    }
    __syncthreads();
    if (tid < NBINS) binBase[tid] = (s - v) + wsum[w];
    if (tid == 0) offs[N_NODES] = E;
}

__global__ __launch_bounds__(256) void binscat_kernel(const int* __restrict__ src, const int* __restrict__ dst,
                                                      const int* __restrict__ cntMat,
                                                      const int* __restrict__ binBase,
                                                      unsigned* __restrict__ binned, int E) {
    __shared__ int cur[512];
    const int tid = threadIdx.x;
    const int row = blockIdx.x;
    for (int j = tid; j < NBINS; j += 256) cur[j] = cntMat[(size_t)row * NBINS + j] + binBase[j];
    __syncthreads();
    int base = row * CHUNK;
    int end = base + CHUNK; if (end > E) end = E;
    for (int i = base + tid; i < end; i += 256) {
        int d = dst[i];
        int s = src[i];
        int bin = d >> 8;
        int pos = atomicAdd(&cur[bin], 1);
        binned[pos] = (unsigned)s | ((unsigned)(d & 255) << 20);
    }
}

__global__ __launch_bounds__(256) void bincsr_kernel(const unsigned* __restrict__ binned,
                                                     const int* __restrict__ binBase, const int* __restrict__ binCnt,
                                                     int* __restrict__ esrc, int* __restrict__ offs) {
    __shared__ int h[256];
    __shared__ int cur[256];
    __shared__ int ssrc[8192];
    const int tid = threadIdx.x;
    const int bin = blockIdx.x;
    const int base = binBase[bin];
    const int cnt = binCnt[bin];
    h[tid] = 0;
    __syncthreads();
    for (int i = tid; i < cnt; i += 256) atomicAdd(&h[binned[base + i] >> 20], 1);
    __syncthreads();
    int v = h[tid];
    for (int o = 1; o < 256; o <<= 1) {
        int t = (tid >= o) ? h[tid - o] : 0;
        __syncthreads();
        h[tid] += t;
        __syncthreads();
    }
    int excl = h[tid] - v;
    cur[tid] = excl;
    int node = (bin << 8) + tid;
    if (node < N_NODES) offs[node] = base + excl;
    __syncthreads();
    for (int i = tid; i < cnt; i += 256) {
        unsigned p = binned[base + i];
        int pos = atomicAdd(&cur[p >> 20], 1);
        int s = (int)(p & 0xFFFFFu);
        if (pos < 8192) ssrc[pos] = s;
        else esrc[base + pos] = s;
    }
    __syncthreads();
    int lim = cnt < 8192 ? cnt : 8192;
    for (int i = tid; i < lim; i += 256) esrc[base + i] = ssrc[i];
}

// ---------------- fused layer v2: gather-mean -> LDS; h-fragments from global regs ----------------
// block = 64 nodes, 256 threads / 4 waves. LDS = mean tile only (16 KB) + sred.
__global__ __launch_bounds__(256, 5) void fused_kernel(const unsigned short* __restrict__ hin,
                                                       const int* __restrict__ offs,
                                                       const int* __restrict__ esrc,
                                                       const unsigned short* __restrict__ Bp,
                                                       const float* __restrict__ bias,
                                                       const float* __restrict__ Wsl,
                                                       unsigned short* __restrict__ hout,
                                                       float* __restrict__ score,
                                                       const float* __restrict__ rrs,
                                                       const float* __restrict__ bsp,
                                                       const float* __restrict__ alphap,
                                                       float* __restrict__ outF,
                                                       const int accum, const int writeH, const int doFinal) {
    __shared__ unsigned short At[64 * 128];   // mean tile, swizzled
    __shared__ float sred[2][64];
    const int tid = threadIdx.x;
    const int lane = tid & 63;
    const int w = tid >> 6;
    const int rowBase = blockIdx.x * 64;

    // (a) gather-mean: each wave owns 16 nodes; uint2/lane, 2 rows per load pass
    const int half = lane >> 5;
    const int fl = lane & 31;
    for (int k = 0; k < 16; ++k) {
        const int nl = w * 16 + k;
        const int node = rowBase + nl;
        float a0 = 0.f, a1 = 0.f, a2 = 0.f, a3 = 0.f;
        int nb = 0;
        if (node < N_NODES) {
            const int beg = offs[node], end = offs[node + 1];
            nb = end - beg;
            for (int base = 0; base < nb; base += 64) {
                int m = nb - base; if (m > 64) m = 64;
                int sv = (lane < m) ? esrc[beg + base + lane] : 0;
                int j = 0;
                for (; j + 16 <= m; j += 16) {
                    uint2 v[8];
                    #pragma unroll
                    for (int p = 0; p < 8; ++p) {
                        int s = __shfl(sv, j + 2 * p + half, 64);
                        v[p] = *(const uint2*)(hin + (size_t)s * HID + fl * 4);
                    }
                    #pragma unroll
                    for (int p = 0; p < 8; ++p) {
                        a0 += bflo(v[p].x); a1 += bfhi(v[p].x);
                        a2 += bflo(v[p].y); a3 += bfhi(v[p].y);
                    }
                }
                for (; j + 2 <= m; j += 2) {
                    int s = __shfl(sv, j + half, 64);
                    uint2 vv = *(const uint2*)(hin + (size_t)s * HID + fl * 4);
                    a0 += bflo(vv.x); a1 += bfhi(vv.x);
                    a2 += bflo(vv.y); a3 += bfhi(vv.y);
                }
                if (j < m) {
                    int s = __shfl(sv, j, 64);
                    if (half == 0) {
                        uint2 vv = *(const uint2*)(hin + (size_t)s * HID + fl * 4);
                        a0 += bflo(vv.x); a1 += bfhi(vv.x);
                        a2 += bflo(vv.y); a3 += bfhi(vv.y);
                    }
                }
            }
        }
        a0 += __shfl_xor(a0, 32, 64);
        a1 += __shfl_xor(a1, 32, 64);
        a2 += __shfl_xor(a2, 32, 64);
        a3 += __shfl_xor(a3, 32, 64);
        if (half == 0) {
            float inv = 1.f / (float)(nb > 0 ? nb : 1);
            uint2 o;
            o.x = (unsigned)f2bf(a0 * inv) | ((unsigned)f2bf(a1 * inv) << 16);
            o.y = (unsigned)f2bf(a2 * inv) | ((unsigned)f2bf(a3 * inv) << 16);
            // swizzled mean-tile write: slot' = (fl>>1) ^ (nl&15), half-chunk (fl&1)
            int sw = (fl >> 1) ^ (nl & 15);
            *(uint2*)&At[nl * 128 + sw * 8 + (fl & 1) * 4] = o;
        }
    }
    __syncthreads();

    // (b) MFMA: 4 waves (wm = w&1 row-half, wn = w>>1 col-half)
    // t=0 (K 0..127): mean from LDS (swizzled). t=1 (K 128..255): h from global regs.
    const int wm = w & 1, wn = w >> 1;
    const int halfRow = lane & 15;
    const int g = lane >> 4;

    floatx4 acc[2][4];
    #pragma unroll
    for (int m = 0; m < 2; m++)
        #pragma unroll
        for (int n = 0; n < 4; n++) acc[m][n] = (floatx4){0.f, 0.f, 0.f, 0.f};

    const int row0 = wm * 32 + halfRow;
    const unsigned short* hrow0 = hin + (size_t)(rowBase + row0) * HID;

    #pragma unroll
    for (int s = 0; s < 4; s++) {
        // t = 0: mean half
        {
            int slot = (s * 4 + g) ^ halfRow;
            short8v a0 = *(const short8v*)&At[row0 * 128 + slot * 8];
            short8v a1 = *(const short8v*)&At[(row0 + 16) * 128 + slot * 8];
            #pragma unroll
            for (int n = 0; n < 4; n++) {
                int col = wn * 64 + n * 16 + halfRow;
                short8v b = *(const short8v*)&Bp[((((size_t)s) * 128 + col) * 4 + g) * 8];
                acc[0][n] = __builtin_amdgcn_mfma_f32_16x16x32_bf16(a0, b, acc[0][n], 0, 0, 0);
                acc[1][n] = __builtin_amdgcn_mfma_f32_16x16x32_bf16(a1, b, acc[1][n], 0, 0, 0);
            }
        }
        // t = 1: h half (fragments straight from global)
        {
            int slot = s * 4 + g;
            short8v a0 = *(const short8v*)(hrow0 + slot * 8);
            short8v a1 = *(const short8v*)(hrow0 + 16 * HID + slot * 8);
            #pragma unroll
            for (int n = 0; n < 4; n++) {
                int col = wn * 64 + n * 16 + halfRow;
                short8v b = *(const short8v*)&Bp[((((size_t)(4 + s)) * 128 + col) * 4 + g) * 8];
                acc[0][n] = __builtin_amdgcn_mfma_f32_16x16x32_bf16(a0, b, acc[0][n], 0, 0, 0);
                acc[1][n] = __builtin_amdgcn_mfma_f32_16x16x32_bf16(a1, b, acc[1][n], 0, 0, 0);
            }
        }
    }

    // (c) epilogue: bias + ReLU + bf16 store + per-row score partial (+ optional final blend)
    #pragma unroll
    for (int m = 0; m < 2; m++) {
        #pragma unroll
        for (int i = 0; i < 4; i++) {
            int rloc = wm * 32 + m * 16 + g * 4 + i;
            int grow = rowBase + rloc;
            float ps = 0.f;
            #pragma unroll
            for (int n = 0; n < 4; n++) {
                int col = wn * 64 + n * 16 + halfRow;
                float v = acc[m][n][i] + bias[col];
                v = fmaxf(v, 0.f);
                if (writeH && grow < N_NODES) hout[(size_t)grow * HID + col] = f2bf(v);
                ps += v * Wsl[col];
            }
            ps += __shfl_xor(ps, 1, 64);
            ps += __shfl_xor(ps, 2, 64);
            ps += __shfl_xor(ps, 4, 64);
            ps += __shfl_xor(ps, 8, 64);
            if (halfRow == 0) sred[wn][rloc] = ps;
        }
    }
    __syncthreads();
    if (w == 0) {
        int grow = rowBase + lane;
        if (grow < N_NODES) {
            float tot = sred[0][lane] + sred[1][lane];
            if (doFinal) {
                float sc = score[grow] + tot;
                float a = 1.f / (1.f + __expf(-alphap[0]));
                outF[grow] = a * rrs[grow] + (1.f - a) * (sc + bsp[0]);
            } else {
                score[grow] = accum ? (score[grow] + tot) : tot;
            }
        }
    }
}

extern "C" void kernel_launch(void* const* d_in, const int* in_sizes, int n_in,
                              void* d_out, int out_size, void* d_ws, size_t ws_size,
                              hipStream_t stream) {
    const float* x     = (const float*)d_in[0];
    const int*   eidx  = (const int*)d_in[1];
    const float* rrs   = (const float*)d_in[2];
    const float* Wl0   = (const float*)d_in[3];
    const float* Wr0   = (const float*)d_in[4];
    const float* b0    = (const float*)d_in[5];
    const float* Wl1   = (const float*)d_in[6];
    const float* Wr1   = (const float*)d_in[7];
    const float* b1    = (const float*)d_in[8];
    const float* Wl2   = (const float*)d_in[9];
    const float* Wr2   = (const float*)d_in[10];
    const float* b2    = (const float*)d_in[11];
    const float* Ws    = (const float*)d_in[12];
    const float* bs    = (const float*)d_in[13];
    const float* alpha = (const float*)d_in[14];

    const int N = N_NODES;
    const int E = in_sizes[1] / 2;
    const int* src = eidx;
    const int* dst = eidx + E;

    uintptr_t p = (uintptr_t)d_ws;
    auto alloc = [&](size_t bytes) -> void* {
        p = (p + 255) & ~(uintptr_t)255;
        void* r = (void*)p;
        p += bytes;
        return r;
    };
    int*            offs    = (int*)alloc((size_t)(N + 1) * 4);
    int*            esrc    = (int*)alloc((size_t)E * 4);
    float*          score   = (float*)alloc((size_t)N * 4);
    int*            binBase = (int*)alloc(512 * 4);
    int*            binCnt  = (int*)alloc(512 * 4);
    unsigned short* xb      = (unsigned short*)alloc((size_t)N * HID * 2);
    unsigned short* bufA    = (unsigned short*)alloc((size_t)N * HID * 2);
    unsigned short* bufB    = (unsigned short*)alloc((size_t)N * HID * 2);
    unsigned short* Bp      = (unsigned short*)alloc((size_t)3 * 32768 * 2);

    int*      cntMat = (int*)bufA;
    unsigned* binned = (unsigned*)bufB;

    const int nch = (E + CHUNK - 1) / CHUNK;   // 391

    prep_kernel<<<N * HID / 8 / 256 + 48, 256, 0, stream>>>(x, xb, N * HID / 8,
                                                            Wl0, Wr0, Wl1, Wr1, Wl2, Wr2, Bp);

    binhist_kernel<<<nch, 256, 0, stream>>>(dst, cntMat, E);
    colscan_kernel<<<NBINS, 512, 0, stream>>>(cntMat, binCnt, nch);
    binbase_kernel<<<1, 512, 0, stream>>>(binCnt, binBase, offs, E);
    binscat_kernel<<<nch, 256, 0, stream>>>(src, dst, cntMat, binBase, binned, E);
    bincsr_kernel<<<NBINS, 256, 0, stream>>>(binned, binBase, binCnt, esrc, offs);

    const int gemmGrid = (N + 63) / 64;   // 1563
    float* outF = (float*)d_out;

    // layer 0: hin = xb, hout = bufA
    fused_kernel<<<gemmGrid, 256, 0, stream>>>(xb, offs, esrc, Bp + 0 * 32768, b0, Ws + 0 * HID,
                                               bufA, score, rrs, bs, alpha, outF, 0, 1, 0);
    // layer 1: hin = bufA, hout = bufB
    fused_kernel<<<gemmGrid, 256, 0, stream>>>(bufA, offs, esrc, Bp + 1 * 32768, b1, Ws + 1 * HID,
                                               bufB, score, rrs, bs, alpha, outF, 1, 1, 0);
    // layer 2: hin = bufB, final blend into d_out
    fused_kernel<<<gemmGrid, 256, 0, stream>>>(bufB, offs, esrc, Bp + 2 * 32768, b2, Ws + 2 * HID,
                                               bufB, score, rrs, bs, alpha, outF, 1, 0, 1);
}

// Round 8
// 334.375 us; speedup vs baseline: 1.2013x; 1.1931x over previous
//
#include <hip/hip_runtime.h>
#include <hip/hip_bf16.h>
#include <cstdint>

#define N_NODES 100000
#define HID 128
#define NBINS 391            // ceil(100000/256)
#define CHUNK 4096

typedef __attribute__((ext_vector_type(8))) short short8v;
typedef __attribute__((ext_vector_type(4))) float floatx4;

__device__ __forceinline__ float bflo(unsigned v) { return __uint_as_float(v << 16); }
__device__ __forceinline__ float bfhi(unsigned v) { return __uint_as_float(v & 0xffff0000u); }
__device__ __forceinline__ unsigned short f2bf(float f) {
    unsigned u = __float_as_uint(f);
    unsigned r = (u + 0x7fffu + ((u >> 16) & 1u)) >> 16;
    return (unsigned short)r;
}

// ---------------- prep: fp32->bf16 convert (x) + weight pack, one launch ----------------
__global__ __launch_bounds__(256) void prep_kernel(const float* __restrict__ x,
                                                   unsigned short* __restrict__ xb, int total8,
                                                   const float* __restrict__ Wl0, const float* __restrict__ Wr0,
                                                   const float* __restrict__ Wl1, const float* __restrict__ Wr1,
                                                   const float* __restrict__ Wl2, const float* __restrict__ Wr2,
                                                   unsigned short* __restrict__ Bp) {
    if ((int)blockIdx.x < total8 / 256) {
        int i = blockIdx.x * 256 + threadIdx.x;
        const float4* p = (const float4*)x + (size_t)i * 2;
        float4 a = p[0], b = p[1];
        uint4 o;
        o.x = f2bf(a.x) | ((unsigned)f2bf(a.y) << 16);
        o.y = f2bf(a.z) | ((unsigned)f2bf(a.w) << 16);
        o.z = f2bf(b.x) | ((unsigned)f2bf(b.y) << 16);
        o.w = f2bf(b.z) | ((unsigned)f2bf(b.w) << 16);
        *(uint4*)(xb + (size_t)i * 8) = o;
    } else {
        int idx = ((int)blockIdx.x - total8 / 256) * 256 + threadIdx.x;
        if (idx >= 12288) return;
        int g = idx & 3, c = (idx >> 2) & 127, s = (idx >> 9) & 3, t = (idx >> 11) & 1, L = idx >> 12;
        const float* W = (t == 0) ? (L == 0 ? Wl0 : (L == 1 ? Wl1 : Wl2))
                                  : (L == 0 ? Wr0 : (L == 1 ? Wr1 : Wr2));
        int k0 = s * 32 + g * 8;
        uint4 o;
        o.x = f2bf(W[(k0 + 0) * 128 + c]) | ((unsigned)f2bf(W[(k0 + 1) * 128 + c]) << 16);
        o.y = f2bf(W[(k0 + 2) * 128 + c]) | ((unsigned)f2bf(W[(k0 + 3) * 128 + c]) << 16);
        o.z = f2bf(W[(k0 + 4) * 128 + c]) | ((unsigned)f2bf(W[(k0 + 5) * 128 + c]) << 16);
        o.w = f2bf(W[(k0 + 6) * 128 + c]) | ((unsigned)f2bf(W[(k0 + 7) * 128 + c]) << 16);
        size_t chunk = (((size_t)(L * 2 + t) * 4 + s) * 128 + c) * 4 + g;
        *(uint4*)(Bp + chunk * 8) = o;
    }
}

// ---------------- CSR build: atomic-free bucket sort ----------------

__global__ __launch_bounds__(256) void binhist_kernel(const int* __restrict__ dst,
                                                      int* __restrict__ cntMat, int E) {
    __shared__ int lcnt[512];
    const int tid = threadIdx.x;
    lcnt[tid] = 0; lcnt[tid + 256] = 0;
    __syncthreads();
    int base = blockIdx.x * CHUNK;
    int end = base + CHUNK; if (end > E) end = E;
    for (int i = base + tid; i < end; i += 256) atomicAdd(&lcnt[dst[i] >> 8], 1);
    __syncthreads();
    for (int j = tid; j < NBINS; j += 256) cntMat[(size_t)blockIdx.x * NBINS + j] = lcnt[j];
}

__global__ __launch_bounds__(512) void colscan_kernel(int* __restrict__ cntMat,
                                                      int* __restrict__ binCnt, int nch) {
    __shared__ int wsum[8];
    const int j = blockIdx.x;
    const int tid = threadIdx.x;
    const int lane = tid & 63, w = tid >> 6;
    int v = (tid < nch) ? cntMat[(size_t)tid * NBINS + j] : 0;
    int s = v;
    #pragma unroll
    for (int o = 1; o < 64; o <<= 1) {
        int t = __shfl_up(s, o, 64);
        if (lane >= o) s += t;
    }
    if (lane == 63) wsum[w] = s;
    __syncthreads();
    if (w == 0 && lane < 8) {
        int t = wsum[lane];
        int ss = t;
        #pragma unroll
        for (int o = 1; o < 8; o <<= 1) {
            int u = __shfl_up(ss, o, 64);
            if (lane >= o) ss += u;
        }
        wsum[lane] = ss - t;
    }
    __syncthreads();
    int excl = (s - v) + wsum[w];
    if (tid < nch) cntMat[(size_t)tid * NBINS + j] = excl;
    if (tid == 511) binCnt[j] = excl + v;
}

__global__ __launch_bounds__(512) void binbase_kernel(const int* __restrict__ binCnt,
                                                      int* __restrict__ binBase,
                                                      int* __restrict__ offs, int E) {
    __shared__ int wsum[8];
    const int tid = threadIdx.x;
    const int lane = tid & 63, w = tid >> 6;
    int v = (tid < NBINS) ? binCnt[tid] : 0;
    int s = v;
    #pragma unroll
    for (int o = 1; o < 64; o <<= 1) {
        int t = __shfl_up(s, o, 64);
        if (lane >= o) s += t;
    }
    if (lane == 63) wsum[w] = s;
    __syncthreads();
    if (w == 0 && lane < 8) {
        int t = wsum[lane];
        int ss = t;
        #pragma unroll
        for (int o = 1; o < 8; o <<= 1) {
            int u = __shfl_up(ss, o, 64);
            if (lane >= o) ss += u;
        }
        wsum[lane] = ss - t;
    }
    __syncthreads();
    if (tid < NBINS) binBase[tid] = (s - v) + wsum[w];
    if (tid == 0) offs[N_NODES] = E;
}

__global__ __launch_bounds__(256) void binscat_kernel(const int* __restrict__ src, const int* __restrict__ dst,
                                                      const int* __restrict__ cntMat,
                                                      const int* __restrict__ binBase,
                                                      unsigned* __restrict__ binned, int E) {
    __shared__ int cur[512];
    const int tid = threadIdx.x;
    const int row = blockIdx.x;
    for (int j = tid; j < NBINS; j += 256) cur[j] = cntMat[(size_t)row * NBINS + j] + binBase[j];
    __syncthreads();
    int base = row * CHUNK;
    int end = base + CHUNK; if (end > E) end = E;
    for (int i = base + tid; i < end; i += 256) {
        int d = dst[i];
        int s = src[i];
        int bin = d >> 8;
        int pos = atomicAdd(&cur[bin], 1);
        binned[pos] = (unsigned)s | ((unsigned)(d & 255) << 20);
    }
}

__global__ __launch_bounds__(256) void bincsr_kernel(const unsigned* __restrict__ binned,
                                                     const int* __restrict__ binBase, const int* __restrict__ binCnt,
                                                     int* __restrict__ esrc, int* __restrict__ offs) {
    __shared__ int h[256];
    __shared__ int cur[256];
    __shared__ int ssrc[8192];
    const int tid = threadIdx.x;
    const int bin = blockIdx.x;
    const int base = binBase[bin];
    const int cnt = binCnt[bin];
    h[tid] = 0;
    __syncthreads();
    for (int i = tid; i < cnt; i += 256) atomicAdd(&h[binned[base + i] >> 20], 1);
    __syncthreads();
    int v = h[tid];
    for (int o = 1; o < 256; o <<= 1) {
        int t = (tid >= o) ? h[tid - o] : 0;
        __syncthreads();
        h[tid] += t;
        __syncthreads();
    }
    int excl = h[tid] - v;
    cur[tid] = excl;
    int node = (bin << 8) + tid;
    if (node < N_NODES) offs[node] = base + excl;
    __syncthreads();
    for (int i = tid; i < cnt; i += 256) {
        unsigned p = binned[base + i];
        int pos = atomicAdd(&cur[p >> 20], 1);
        int s = (int)(p & 0xFFFFFu);
        if (pos < 8192) ssrc[pos] = s;
        else esrc[base + pos] = s;
    }
    __syncthreads();
    int lim = cnt < 8192 ? cnt : 8192;
    for (int i = tid; i < lim; i += 256) esrc[base + i] = ssrc[i];
}

// ---------------- mean aggregation: uint2/lane, 2 rows per load, 16 rows in flight ----------------
__global__ __launch_bounds__(256) void agg_kernel(const unsigned short* __restrict__ h,
                                                  const int* __restrict__ offs,
                                                  const int* __restrict__ esrc,
                                                  unsigned short* __restrict__ mean) {
    const int lane = threadIdx.x & 63;
    const int node = blockIdx.x * 4 + (threadIdx.x >> 6);
    const int half = lane >> 5;
    const int fl = lane & 31;
    const int beg = offs[node], end = offs[node + 1];
    const int nb = end - beg;
    float a0 = 0.f, a1 = 0.f, a2 = 0.f, a3 = 0.f;
    for (int base = 0; base < nb; base += 64) {
        int m = nb - base; if (m > 64) m = 64;
        int sv = (lane < m) ? esrc[beg + base + lane] : 0;
        int j = 0;
        for (; j + 16 <= m; j += 16) {
            uint2 v[8];
            #pragma unroll
            for (int p = 0; p < 8; ++p) {
                int s = __shfl(sv, j + 2 * p + half, 64);
                v[p] = *(const uint2*)(h + (size_t)s * HID + fl * 4);
            }
            #pragma unroll
            for (int p = 0; p < 8; ++p) {
                a0 += bflo(v[p].x); a1 += bfhi(v[p].x);
                a2 += bflo(v[p].y); a3 += bfhi(v[p].y);
            }
        }
        for (; j + 2 <= m; j += 2) {
            int s = __shfl(sv, j + half, 64);
            uint2 vv = *(const uint2*)(h + (size_t)s * HID + fl * 4);
            a0 += bflo(vv.x); a1 += bfhi(vv.x);
            a2 += bflo(vv.y); a3 += bfhi(vv.y);
        }
        if (j < m) {
            int s = __shfl(sv, j, 64);
            if (half == 0) {
                uint2 vv = *(const uint2*)(h + (size_t)s * HID + fl * 4);
                a0 += bflo(vv.x); a1 += bfhi(vv.x);
                a2 += bflo(vv.y); a3 += bfhi(vv.y);
            }
        }
    }
    a0 += __shfl_xor(a0, 32, 64);
    a1 += __shfl_xor(a1, 32, 64);
    a2 += __shfl_xor(a2, 32, 64);
    a3 += __shfl_xor(a3, 32, 64);
    if (half == 0) {
        float inv = 1.f / (float)(nb > 0 ? nb : 1);
        uint2 o;
        o.x = (unsigned)f2bf(a0 * inv) | ((unsigned)f2bf(a1 * inv) << 16);
        o.y = (unsigned)f2bf(a2 * inv) | ((unsigned)f2bf(a3 * inv) << 16);
        *(uint2*)(mean + (size_t)node * HID + fl * 4) = o;
    }
}

// ---------------- MFMA GEMM: out = relu([mean|h]@[Wl;Wr] + b); score (+)= out@Wsl ----------------
// stage only mean tile; h-fragments direct from global; coalesced LDS-staged output
__global__ __launch_bounds__(256) void gemm_kernel(const unsigned short* __restrict__ Am,
                                                   const unsigned short* __restrict__ Ah,
                                                   const unsigned short* __restrict__ Bp,
                                                   const float* __restrict__ bias,
                                                   const float* __restrict__ Wsl,
                                                   unsigned short* __restrict__ hout,
                                                   float* __restrict__ score,
                                                   const float* __restrict__ rrs,
                                                   const float* __restrict__ bsp,
                                                   const float* __restrict__ alphap,
                                                   float* __restrict__ outF,
                                                   const int accum, const int writeH, const int doFinal) {
    __shared__ unsigned short At[64 * 136];   // stage region uses first 8192; out-stage stride 136
    __shared__ float sred[2][64];
    const int tid = threadIdx.x;
    const int lane = tid & 63;
    const int w = tid >> 6;
    const int wm = w & 1, wn = w >> 1;
    const int rowBase = blockIdx.x * 64;
    const int halfRow = lane & 15;
    const int g = lane >> 4;

    // stage mean tile via global_load_lds (pre-swizzled source: slot' = slot ^ (row&15))
    #pragma unroll
    for (int r = 0; r < 4; ++r) {
        int c = r * 256 + tid;
        int row = c >> 4, slot = c & 15;
        int gslot = slot ^ (row & 15);
        int grow = rowBase + row; if (grow >= N_NODES) grow = N_NODES - 1;
        const unsigned short* gp = Am + (size_t)grow * HID + gslot * 8;
        unsigned ldsOff = (unsigned)(r * 4096 + w * 1024);
        __builtin_amdgcn_global_load_lds((const __attribute__((address_space(1))) void*)gp,
                                         (__attribute__((address_space(3))) void*)((char*)At + ldsOff),
                                         16, 0, 0);
    }
    __syncthreads();

    floatx4 acc[2][4];
    #pragma unroll
    for (int m = 0; m < 2; m++)
        #pragma unroll
        for (int n = 0; n < 4; n++) acc[m][n] = (floatx4){0.f, 0.f, 0.f, 0.f};

    const int row0 = wm * 32 + halfRow;
    const unsigned short* hrow0 = Ah + (size_t)(rowBase + row0) * HID;

    #pragma unroll
    for (int s = 0; s < 4; s++) {
        // t = 0: mean half from LDS (swizzled)
        {
            int slot = (s * 4 + g) ^ halfRow;
            short8v a0 = *(const short8v*)&At[row0 * 128 + slot * 8];
            short8v a1 = *(const short8v*)&At[(row0 + 16) * 128 + slot * 8];
            #pragma unroll
            for (int n = 0; n < 4; n++) {
                int col = wn * 64 + n * 16 + halfRow;
                short8v b = *(const short8v*)&Bp[((((size_t)s) * 128 + col) * 4 + g) * 8];
                acc[0][n] = __builtin_amdgcn_mfma_f32_16x16x32_bf16(a0, b, acc[0][n], 0, 0, 0);
                acc[1][n] = __builtin_amdgcn_mfma_f32_16x16x32_bf16(a1, b, acc[1][n], 0, 0, 0);
            }
        }
        // t = 1: h half, fragments direct from global (broadcast 16B reads, L2/L3-hot)
        {
            int slot = s * 4 + g;
            short8v a0 = *(const short8v*)(hrow0 + slot * 8);
            short8v a1 = *(const short8v*)(hrow0 + 16 * HID + slot * 8);
            #pragma unroll
            for (int n = 0; n < 4; n++) {
                int col = wn * 64 + n * 16 + halfRow;
                short8v b = *(const short8v*)&Bp[((((size_t)(4 + s)) * 128 + col) * 4 + g) * 8];
                acc[0][n] = __builtin_amdgcn_mfma_f32_16x16x32_bf16(a0, b, acc[0][n], 0, 0, 0);
                acc[1][n] = __builtin_amdgcn_mfma_f32_16x16x32_bf16(a1, b, acc[1][n], 0, 0, 0);
            }
        }
    }

    __syncthreads();   // all waves done reading stage region before overwrite

    // epilogue: bias + ReLU; bf16 out staged to LDS (stride 136); per-row score partial
    #pragma unroll
    for (int m = 0; m < 2; m++) {
        #pragma unroll
        for (int i = 0; i < 4; i++) {
            int rloc = wm * 32 + m * 16 + g * 4 + i;
            float ps = 0.f;
            #pragma unroll
            for (int n = 0; n < 4; n++) {
                int col = wn * 64 + n * 16 + halfRow;
                float v = acc[m][n][i] + bias[col];
                v = fmaxf(v, 0.f);
                if (writeH) At[rloc * 136 + col] = f2bf(v);
                ps += v * Wsl[col];
            }
            ps += __shfl_xor(ps, 1, 64);
            ps += __shfl_xor(ps, 2, 64);
            ps += __shfl_xor(ps, 4, 64);
            ps += __shfl_xor(ps, 8, 64);
            if (halfRow == 0) sred[wn][rloc] = ps;
        }
    }
    __syncthreads();

    if (writeH) {
        #pragma unroll
        for (int p2 = 0; p2 < 4; ++p2) {
            int lin = p2 * 256 + tid;
            int row = lin >> 4, q = lin & 15;
            int grow = rowBase + row;
            if (grow < N_NODES)
                *(uint4*)(hout + (size_t)grow * HID + q * 8) = *(const uint4*)&At[row * 136 + q * 8];
        }
    }

    if (w == 0) {
        int grow = rowBase + lane;
        if (grow < N_NODES) {
            float tot = sred[0][lane] + sred[1][lane];
            if (doFinal) {
                float sc = score[grow] + tot;
                float a = 1.f / (1.f + __expf(-alphap[0]));
                outF[grow] = a * rrs[grow] + (1.f - a) * (sc + bsp[0]);
            } else {
                score[grow] = accum ? (score[grow] + tot) : tot;
            }
        }
    }
}

extern "C" void kernel_launch(void* const* d_in, const int* in_sizes, int n_in,
                              void* d_out, int out_size, void* d_ws, size_t ws_size,
                              hipStream_t stream) {
    const float* x     = (const float*)d_in[0];
    const int*   eidx  = (const int*)d_in[1];
    const float* rrs   = (const float*)d_in[2];
    const float* Wl0   = (const float*)d_in[3];
    const float* Wr0   = (const float*)d_in[4];
    const float* b0    = (const float*)d_in[5];
    const float* Wl1   = (const float*)d_in[6];
    const float* Wr1   = (const float*)d_in[7];
    const float* b1    = (const float*)d_in[8];
    const float* Wl2   = (const float*)d_in[9];
    const float* Wr2   = (const float*)d_in[10];
    const float* b2    = (const float*)d_in[11];
    const float* Ws    = (const float*)d_in[12];
    const float* bs    = (const float*)d_in[13];
    const float* alpha = (const float*)d_in[14];

    const int N = N_NODES;
    const int E = in_sizes[1] / 2;
    const int* src = eidx;
    const int* dst = eidx + E;

    uintptr_t p = (uintptr_t)d_ws;
    auto alloc = [&](size_t bytes) -> void* {
        p = (p + 255) & ~(uintptr_t)255;
        void* r = (void*)p;
        p += bytes;
        return r;
    };
    int*            offs    = (int*)alloc((size_t)(N + 1) * 4);
    int*            esrc    = (int*)alloc((size_t)E * 4);
    float*          score   = (float*)alloc((size_t)N * 4);
    int*            binBase = (int*)alloc(512 * 4);
    int*            binCnt  = (int*)alloc(512 * 4);
    unsigned short* xb      = (unsigned short*)alloc((size_t)N * HID * 2);
    unsigned short* bufA    = (unsigned short*)alloc((size_t)N * HID * 2);
    unsigned short* bufB    = (unsigned short*)alloc((size_t)N * HID * 2);
    unsigned short* Bp      = (unsigned short*)alloc((size_t)3 * 32768 * 2);

    int*      cntMat = (int*)bufA;
    unsigned* binned = (unsigned*)bufB;

    const int nch = (E + CHUNK - 1) / CHUNK;   // 391

    prep_kernel<<<N * HID / 8 / 256 + 48, 256, 0, stream>>>(x, xb, N * HID / 8,
                                                            Wl0, Wr0, Wl1, Wr1, Wl2, Wr2, Bp);

    binhist_kernel<<<nch, 256, 0, stream>>>(dst, cntMat, E);
    colscan_kernel<<<NBINS, 512, 0, stream>>>(cntMat, binCnt, nch);
    binbase_kernel<<<1, 512, 0, stream>>>(binCnt, binBase, offs, E);
    binscat_kernel<<<nch, 256, 0, stream>>>(src, dst, cntMat, binBase, binned, E);
    bincsr_kernel<<<NBINS, 256, 0, stream>>>(binned, binBase, binCnt, esrc, offs);

    const int aggGrid  = N / 4;            // 25000
    const int gemmGrid = (N + 63) / 64;    // 1563
    float* outF = (float*)d_out;

    // layer 0
    agg_kernel<<<aggGrid, 256, 0, stream>>>(xb, offs, esrc, bufA);
    gemm_kernel<<<gemmGrid, 256, 0, stream>>>(bufA, xb, Bp + 0 * 32768, b0, Ws + 0 * HID, bufA, score,
                                              rrs, bs, alpha, outF, 0, 1, 0);
    // layer 1
    agg_kernel<<<aggGrid, 256, 0, stream>>>(bufA, offs, esrc, bufB);
    gemm_kernel<<<gemmGrid, 256, 0, stream>>>(bufB, bufA, Bp + 1 * 32768, b1, Ws + 1 * HID, bufB, score,
                                              rrs, bs, alpha, outF, 1, 1, 0);
    // layer 2
    agg_kernel<<<aggGrid, 256, 0, stream>>>(bufB, offs, esrc, bufA);
    gemm_kernel<<<gemmGrid, 256, 0, stream>>>(bufA, bufB, Bp + 2 * 32768, b2, Ws + 2 * HID, bufA, score,
                                              rrs, bs, alpha, outF, 1, 0, 1);
}

// Round 9
// 319.466 us; speedup vs baseline: 1.2574x; 1.0467x over previous
//
#include <hip/hip_runtime.h>
#include <hip/hip_bf16.h>
#include <cstdint>

#define N_NODES 100000
#define HID 128
#define NBINS 391            // ceil(100000/256)
#define CHUNK 4096

typedef __attribute__((ext_vector_type(8))) short short8v;
typedef __attribute__((ext_vector_type(4))) float floatx4;

__device__ __forceinline__ float bflo(unsigned v) { return __uint_as_float(v << 16); }
__device__ __forceinline__ float bfhi(unsigned v) { return __uint_as_float(v & 0xffff0000u); }
__device__ __forceinline__ unsigned short f2bf(float f) {
    unsigned u = __float_as_uint(f);
    unsigned r = (u + 0x7fffu + ((u >> 16) & 1u)) >> 16;
    return (unsigned short)r;
}

// ---------------- prep: fp32->bf16 convert (x) + weight pack + edge histogram ----------------
// grid = 6250 (conv) + 48 (packw) + nch (hist)
__global__ __launch_bounds__(256) void prep_kernel(const float* __restrict__ x,
                                                   unsigned short* __restrict__ xb,
                                                   const float* __restrict__ Wl0, const float* __restrict__ Wr0,
                                                   const float* __restrict__ Wl1, const float* __restrict__ Wr1,
                                                   const float* __restrict__ Wl2, const float* __restrict__ Wr2,
                                                   unsigned short* __restrict__ Bp,
                                                   const int* __restrict__ dst,
                                                   int* __restrict__ cntMat, int E) {
    __shared__ int lcnt[512];
    const int bid = blockIdx.x;
    const int tid = threadIdx.x;
    if (bid < 6250) {
        int i = bid * 256 + tid;
        const float4* p = (const float4*)x + (size_t)i * 2;
        float4 a = p[0], b = p[1];
        uint4 o;
        o.x = f2bf(a.x) | ((unsigned)f2bf(a.y) << 16);
        o.y = f2bf(a.z) | ((unsigned)f2bf(a.w) << 16);
        o.z = f2bf(b.x) | ((unsigned)f2bf(b.y) << 16);
        o.w = f2bf(b.z) | ((unsigned)f2bf(b.w) << 16);
        *(uint4*)(xb + (size_t)i * 8) = o;
    } else if (bid < 6298) {
        int idx = (bid - 6250) * 256 + tid;
        if (idx >= 12288) return;
        int g = idx & 3, c = (idx >> 2) & 127, s = (idx >> 9) & 3, t = (idx >> 11) & 1, L = idx >> 12;
        const float* W = (t == 0) ? (L == 0 ? Wl0 : (L == 1 ? Wl1 : Wl2))
                                  : (L == 0 ? Wr0 : (L == 1 ? Wr1 : Wr2));
        int k0 = s * 32 + g * 8;
        uint4 o;
        o.x = f2bf(W[(k0 + 0) * 128 + c]) | ((unsigned)f2bf(W[(k0 + 1) * 128 + c]) << 16);
        o.y = f2bf(W[(k0 + 2) * 128 + c]) | ((unsigned)f2bf(W[(k0 + 3) * 128 + c]) << 16);
        o.z = f2bf(W[(k0 + 4) * 128 + c]) | ((unsigned)f2bf(W[(k0 + 5) * 128 + c]) << 16);
        o.w = f2bf(W[(k0 + 6) * 128 + c]) | ((unsigned)f2bf(W[(k0 + 7) * 128 + c]) << 16);
        size_t chunk = (((size_t)(L * 2 + t) * 4 + s) * 128 + c) * 4 + g;
        *(uint4*)(Bp + chunk * 8) = o;
    } else {
        const int row = bid - 6298;
        lcnt[tid] = 0; lcnt[tid + 256] = 0;
        __syncthreads();
        int base = row * CHUNK;
        int end = base + CHUNK; if (end > E) end = E;
        for (int i = base + tid; i < end; i += 256) atomicAdd(&lcnt[dst[i] >> 8], 1);
        __syncthreads();
        for (int j = tid; j < NBINS; j += 256) cntMat[(size_t)row * NBINS + j] = lcnt[j];
    }
}

// ---------------- CSR build: atomic-free bucket sort ----------------

__global__ __launch_bounds__(512) void colscan_kernel(int* __restrict__ cntMat,
                                                      int* __restrict__ binCnt, int nch) {
    __shared__ int wsum[8];
    const int j = blockIdx.x;
    const int tid = threadIdx.x;
    const int lane = tid & 63, w = tid >> 6;
    int v = (tid < nch) ? cntMat[(size_t)tid * NBINS + j] : 0;
    int s = v;
    #pragma unroll
    for (int o = 1; o < 64; o <<= 1) {
        int t = __shfl_up(s, o, 64);
        if (lane >= o) s += t;
    }
    if (lane == 63) wsum[w] = s;
    __syncthreads();
    if (w == 0 && lane < 8) {
        int t = wsum[lane];
        int ss = t;
        #pragma unroll
        for (int o = 1; o < 8; o <<= 1) {
            int u = __shfl_up(ss, o, 64);
            if (lane >= o) ss += u;
        }
        wsum[lane] = ss - t;
    }
    __syncthreads();
    int excl = (s - v) + wsum[w];
    if (tid < nch) cntMat[(size_t)tid * NBINS + j] = excl;
    if (tid == 511) binCnt[j] = excl + v;
}

__global__ __launch_bounds__(512) void binbase_kernel(const int* __restrict__ binCnt,
                                                      int* __restrict__ binBase,
                                                      int* __restrict__ offs, int E) {
    __shared__ int wsum[8];
    const int tid = threadIdx.x;
    const int lane = tid & 63, w = tid >> 6;
    int v = (tid < NBINS) ? binCnt[tid] : 0;
    int s = v;
    #pragma unroll
    for (int o = 1; o < 64; o <<= 1) {
        int t = __shfl_up(s, o, 64);
        if (lane >= o) s += t;
    }
    if (lane == 63) wsum[w] = s;
    __syncthreads();
    if (w == 0 && lane < 8) {
        int t = wsum[lane];
        int ss = t;
        #pragma unroll
        for (int o = 1; o < 8; o <<= 1) {
            int u = __shfl_up(ss, o, 64);
            if (lane >= o) ss += u;
        }
        wsum[lane] = ss - t;
    }
    __syncthreads();
    if (tid < NBINS) binBase[tid] = (s - v) + wsum[w];
    if (tid == 0) offs[N_NODES] = E;
}

__global__ __launch_bounds__(256) void binscat_kernel(const int* __restrict__ src, const int* __restrict__ dst,
                                                      const int* __restrict__ cntMat,
                                                      const int* __restrict__ binBase,
                                                      unsigned* __restrict__ binned, int E) {
    __shared__ int cur[512];
    const int tid = threadIdx.x;
    const int row = blockIdx.x;
    for (int j = tid; j < NBINS; j += 256) cur[j] = cntMat[(size_t)row * NBINS + j] + binBase[j];
    __syncthreads();
    int base = row * CHUNK;
    int end = base + CHUNK; if (end > E) end = E;
    for (int i = base + tid; i < end; i += 256) {
        int d = dst[i];
        int s = src[i];
        int bin = d >> 8;
        int pos = atomicAdd(&cur[bin], 1);
        binned[pos] = (unsigned)s | ((unsigned)(d & 255) << 20);
    }
}

__global__ __launch_bounds__(256) void bincsr_kernel(const unsigned* __restrict__ binned,
                                                     const int* __restrict__ binBase, const int* __restrict__ binCnt,
                                                     int* __restrict__ esrc, int* __restrict__ offs) {
    __shared__ int h[256];
    __shared__ int cur[256];
    __shared__ int ssrc[8192];
    const int tid = threadIdx.x;
    const int bin = blockIdx.x;
    const int base = binBase[bin];
    const int cnt = binCnt[bin];
    h[tid] = 0;
    __syncthreads();
    for (int i = tid; i < cnt; i += 256) atomicAdd(&h[binned[base + i] >> 20], 1);
    __syncthreads();
    int v = h[tid];
    for (int o = 1; o < 256; o <<= 1) {
        int t = (tid >= o) ? h[tid - o] : 0;
        __syncthreads();
        h[tid] += t;
        __syncthreads();
    }
    int excl = h[tid] - v;
    cur[tid] = excl;
    int node = (bin << 8) + tid;
    if (node < N_NODES) offs[node] = base + excl;
    __syncthreads();
    for (int i = tid; i < cnt; i += 256) {
        unsigned p = binned[base + i];
        int pos = atomicAdd(&cur[p >> 20], 1);
        int s = (int)(p & 0xFFFFFu);
        if (pos < 8192) ssrc[pos] = s;
        else esrc[base + pos] = s;
    }
    __syncthreads();
    int lim = cnt < 8192 ? cnt : 8192;
    for (int i = tid; i < lim; i += 256) esrc[base + i] = ssrc[i];
}

// ---------------- mean aggregation: uint2/lane, 2 rows per load, 16 rows in flight ----------------
__global__ __launch_bounds__(256) void agg_kernel(const unsigned short* __restrict__ h,
                                                  const int* __restrict__ offs,
                                                  const int* __restrict__ esrc,
                                                  unsigned short* __restrict__ mean) {
    const int lane = threadIdx.x & 63;
    const int node = blockIdx.x * 4 + (threadIdx.x >> 6);
    const int half = lane >> 5;
    const int fl = lane & 31;
    const int beg = offs[node], end = offs[node + 1];
    const int nb = end - beg;
    float a0 = 0.f, a1 = 0.f, a2 = 0.f, a3 = 0.f;
    for (int base = 0; base < nb; base += 64) {
        int m = nb - base; if (m > 64) m = 64;
        int sv = (lane < m) ? esrc[beg + base + lane] : 0;
        int j = 0;
        for (; j + 16 <= m; j += 16) {
            uint2 v[8];
            #pragma unroll
            for (int p = 0; p < 8; ++p) {
                int s = __shfl(sv, j + 2 * p + half, 64);
                v[p] = *(const uint2*)(h + (size_t)s * HID + fl * 4);
            }
            #pragma unroll
            for (int p = 0; p < 8; ++p) {
                a0 += bflo(v[p].x); a1 += bfhi(v[p].x);
                a2 += bflo(v[p].y); a3 += bfhi(v[p].y);
            }
        }
        for (; j + 2 <= m; j += 2) {
            int s = __shfl(sv, j + half, 64);
            uint2 vv = *(const uint2*)(h + (size_t)s * HID + fl * 4);
            a0 += bflo(vv.x); a1 += bfhi(vv.x);
            a2 += bflo(vv.y); a3 += bfhi(vv.y);
        }
        if (j < m) {
            int s = __shfl(sv, j, 64);
            if (half == 0) {
                uint2 vv = *(const uint2*)(h + (size_t)s * HID + fl * 4);
                a0 += bflo(vv.x); a1 += bfhi(vv.x);
                a2 += bflo(vv.y); a3 += bfhi(vv.y);
            }
        }
    }
    a0 += __shfl_xor(a0, 32, 64);
    a1 += __shfl_xor(a1, 32, 64);
    a2 += __shfl_xor(a2, 32, 64);
    a3 += __shfl_xor(a3, 32, 64);
    if (half == 0) {
        float inv = 1.f / (float)(nb > 0 ? nb : 1);
        uint2 o;
        o.x = (unsigned)f2bf(a0 * inv) | ((unsigned)f2bf(a1 * inv) << 16);
        o.y = (unsigned)f2bf(a2 * inv) | ((unsigned)f2bf(a3 * inv) << 16);
        *(uint2*)(mean + (size_t)node * HID + fl * 4) = o;
    }
}

// ---------------- MFMA GEMM: out = relu([mean|h]@[Wl;Wr] + b); score (+)= out@Wsl ----------------
// both tiles staged via global_load_lds (round-5 path); coalesced LDS-staged output
__global__ __launch_bounds__(256) void gemm_kernel(const unsigned short* __restrict__ Am,
                                                   const unsigned short* __restrict__ Ah,
                                                   const unsigned short* __restrict__ Bp,
                                                   const float* __restrict__ bias,
                                                   const float* __restrict__ Wsl,
                                                   unsigned short* __restrict__ hout,
                                                   float* __restrict__ score,
                                                   const float* __restrict__ rrs,
                                                   const float* __restrict__ bsp,
                                                   const float* __restrict__ alphap,
                                                   float* __restrict__ outF,
                                                   const int accum, const int writeH, const int doFinal) {
    __shared__ unsigned short At[2 * 64 * 128];   // 32KB stage; reused as out-stage (stride 136)
    __shared__ float sred[2][64];
    const int tid = threadIdx.x;
    const int lane = tid & 63;
    const int w = tid >> 6;
    const int wm = w & 1, wn = w >> 1;
    const int rowBase = blockIdx.x * 64;
    const int halfRow = lane & 15;
    const int g = lane >> 4;

    // stage mean + h tiles (pre-swizzled source: slot' = slot ^ (row&15))
    {
        const unsigned short* srcs[2] = { Am, Ah };
        #pragma unroll
        for (int r = 0; r < 8; ++r) {
            int c = r * 256 + tid;
            int sIdx = c >> 10;
            int rem = c & 1023;
            int row = rem >> 4, slot = rem & 15;
            int gslot = slot ^ (row & 15);
            int grow = rowBase + row; if (grow >= N_NODES) grow = N_NODES - 1;
            const unsigned short* gp = srcs[sIdx] + (size_t)grow * HID + gslot * 8;
            unsigned ldsOff = (unsigned)(r * 4096 + w * 1024);
            __builtin_amdgcn_global_load_lds((const __attribute__((address_space(1))) void*)gp,
                                             (__attribute__((address_space(3))) void*)((char*)At + ldsOff),
                                             16, 0, 0);
        }
    }
    __syncthreads();

    floatx4 acc[2][4];
    #pragma unroll
    for (int m = 0; m < 2; m++)
        #pragma unroll
        for (int n = 0; n < 4; n++) acc[m][n] = (floatx4){0.f, 0.f, 0.f, 0.f};

    #pragma unroll
    for (int t = 0; t < 2; t++) {
        #pragma unroll
        for (int s = 0; s < 4; s++) {
            int slot = (s * 4 + g) ^ halfRow;
            int row0 = wm * 32 + halfRow;
            short8v a0 = *(const short8v*)&At[t * 8192 + row0 * 128 + slot * 8];
            short8v a1 = *(const short8v*)&At[t * 8192 + (row0 + 16) * 128 + slot * 8];
            #pragma unroll
            for (int n = 0; n < 4; n++) {
                int col = wn * 64 + n * 16 + halfRow;
                short8v b = *(const short8v*)&Bp[((((size_t)(t * 4 + s)) * 128 + col) * 4 + g) * 8];
                acc[0][n] = __builtin_amdgcn_mfma_f32_16x16x32_bf16(a0, b, acc[0][n], 0, 0, 0);
                acc[1][n] = __builtin_amdgcn_mfma_f32_16x16x32_bf16(a1, b, acc[1][n], 0, 0, 0);
            }
        }
    }

    __syncthreads();   // all waves done reading stage region before out-stage overwrite

    // epilogue: bias + ReLU; out staged to LDS (stride 136); per-row score partial
    #pragma unroll
    for (int m = 0; m < 2; m++) {
        #pragma unroll
        for (int i = 0; i < 4; i++) {
            int rloc = wm * 32 + m * 16 + g * 4 + i;
            float ps = 0.f;
            #pragma unroll
            for (int n = 0; n < 4; n++) {
                int col = wn * 64 + n * 16 + halfRow;
                float v = acc[m][n][i] + bias[col];
                v = fmaxf(v, 0.f);
                if (writeH) At[rloc * 136 + col] = f2bf(v);
                ps += v * Wsl[col];
            }
            ps += __shfl_xor(ps, 1, 64);
            ps += __shfl_xor(ps, 2, 64);
            ps += __shfl_xor(ps, 4, 64);
            ps += __shfl_xor(ps, 8, 64);
            if (halfRow == 0) sred[wn][rloc] = ps;
        }
    }
    __syncthreads();

    if (writeH) {
        #pragma unroll
        for (int p2 = 0; p2 < 4; ++p2) {
            int lin = p2 * 256 + tid;
            int row = lin >> 4, q = lin & 15;
            int grow = rowBase + row;
            if (grow < N_NODES)
                *(uint4*)(hout + (size_t)grow * HID + q * 8) = *(const uint4*)&At[row * 136 + q * 8];
        }
    }

    if (w == 0) {
        int grow = rowBase + lane;
        if (grow < N_NODES) {
            float tot = sred[0][lane] + sred[1][lane];
            if (doFinal) {
                float sc = score[grow] + tot;
                float a = 1.f / (1.f + __expf(-alphap[0]));
                outF[grow] = a * rrs[grow] + (1.f - a) * (sc + bsp[0]);
            } else {
                score[grow] = accum ? (score[grow] + tot) : tot;
            }
        }
    }
}

extern "C" void kernel_launch(void* const* d_in, const int* in_sizes, int n_in,
                              void* d_out, int out_size, void* d_ws, size_t ws_size,
                              hipStream_t stream) {
    const float* x     = (const float*)d_in[0];
    const int*   eidx  = (const int*)d_in[1];
    const float* rrs   = (const float*)d_in[2];
    const float* Wl0   = (const float*)d_in[3];
    const float* Wr0   = (const float*)d_in[4];
    const float* b0    = (const float*)d_in[5];
    const float* Wl1   = (const float*)d_in[6];
    const float* Wr1   = (const float*)d_in[7];
    const float* b1    = (const float*)d_in[8];
    const float* Wl2   = (const float*)d_in[9];
    const float* Wr2   = (const float*)d_in[10];
    const float* b2    = (const float*)d_in[11];
    const float* Ws    = (const float*)d_in[12];
    const float* bs    = (const float*)d_in[13];
    const float* alpha = (const float*)d_in[14];

    const int N = N_NODES;
    const int E = in_sizes[1] / 2;
    const int* src = eidx;
    const int* dst = eidx + E;

    uintptr_t p = (uintptr_t)d_ws;
    auto alloc = [&](size_t bytes) -> void* {
        p = (p + 255) & ~(uintptr_t)255;
        void* r = (void*)p;
        p += bytes;
        return r;
    };
    int*            offs    = (int*)alloc((size_t)(N + 1) * 4);
    int*            esrc    = (int*)alloc((size_t)E * 4);
    float*          score   = (float*)alloc((size_t)N * 4);
    int*            binBase = (int*)alloc(512 * 4);
    int*            binCnt  = (int*)alloc(512 * 4);
    unsigned short* xb      = (unsigned short*)alloc((size_t)N * HID * 2);
    unsigned short* bufA    = (unsigned short*)alloc((size_t)N * HID * 2);
    unsigned short* bufB    = (unsigned short*)alloc((size_t)N * HID * 2);
    unsigned short* Bp      = (unsigned short*)alloc((size_t)3 * 32768 * 2);

    int*      cntMat = (int*)bufA;
    unsigned* binned = (unsigned*)bufB;

    const int nch = (E + CHUNK - 1) / CHUNK;   // 391

    // prep: convert x + pack weights + edge histogram, one launch
    prep_kernel<<<6250 + 48 + nch, 256, 0, stream>>>(x, xb, Wl0, Wr0, Wl1, Wr1, Wl2, Wr2, Bp,
                                                     dst, cntMat, E);

    colscan_kernel<<<NBINS, 512, 0, stream>>>(cntMat, binCnt, nch);
    binbase_kernel<<<1, 512, 0, stream>>>(binCnt, binBase, offs, E);
    binscat_kernel<<<nch, 256, 0, stream>>>(src, dst, cntMat, binBase, binned, E);
    bincsr_kernel<<<NBINS, 256, 0, stream>>>(binned, binBase, binCnt, esrc, offs);

    const int aggGrid  = N / 4;            // 25000
    const int gemmGrid = (N + 63) / 64;    // 1563
    float* outF = (float*)d_out;

    // layer 0
    agg_kernel<<<aggGrid, 256, 0, stream>>>(xb, offs, esrc, bufA);
    gemm_kernel<<<gemmGrid, 256, 0, stream>>>(bufA, xb, Bp + 0 * 32768, b0, Ws + 0 * HID, bufA, score,
                                              rrs, bs, alpha, outF, 0, 1, 0);
    // layer 1
    agg_kernel<<<aggGrid, 256, 0, stream>>>(bufA, offs, esrc, bufB);
    gemm_kernel<<<gemmGrid, 256, 0, stream>>>(bufB, bufA, Bp + 1 * 32768, b1, Ws + 1 * HID, bufB, score,
                                              rrs, bs, alpha, outF, 1, 1, 0);
    // layer 2
    agg_kernel<<<aggGrid, 256, 0, stream>>>(bufB, offs, esrc, bufA);
    gemm_kernel<<<gemmGrid, 256, 0, stream>>>(bufA, bufB, Bp + 2 * 32768, b2, Ws + 2 * HID, bufA, score,
                                              rrs, bs, alpha, outF, 1, 0, 1);
}